// Round 18
// baseline (121.677 us; speedup 1.0000x reference)
//
#include <hip/hip_runtime.h>
#include <hip/hip_cooperative_groups.h>
#include <cstdint>

typedef unsigned long long u64;

#define TOPK 2048          // candidate window for mask+scan
#define MW2 (TOPK / 64)    // 32 suppression words
#define CAND 4096          // max compacted candidates
#define NB 64              // cooperative grid blocks
#define NT 256             // threads per block
#define HIST_BLOCKS 8
#define NTILES ((MW2 * (MW2 + 1)) / 2)   // 528 triangular mask tiles
#define FB_WORDS 1024
#define BAR_MAGIC 0x13579BDF2468ACE0ull
#define SPIN_CAP 400000000LL

__device__ __forceinline__ unsigned score_ud(float s, float thr) {
    unsigned u = __float_as_uint(s);
    u ^= (u >> 31) ? 0xFFFFFFFFu : 0x80000000u;   // orderable ascending
    unsigned ud = ~u;                              // ascending ud = descending score
    if (!(s > thr)) ud = 0xFFFFFFFFu;              // below threshold -> invalid
    return ud;
}

struct Bar { u64 ready; int cnt; int sense; int ticket; int pad; };

struct SM {
    union {
        int bins[4096];                            // 16 KB: hist / cutoff
        u64 rkeys[CAND];                           // 32 KB: rank
        struct {                                   // 7 KB: mask tiles (4 wave-groups)
            float jx1[4][64], jy1[4][64], jx2[4][64], jy2[4][64], ja[4][64];
            u64 rowLDS[4][64];
        } mk;
        struct {                                   // 32 KB: scan
            u64 diagLDS[TOPK];
            int selLDS[TOPK];
            u64 aliveW[FB_WORDS];
        } sc;
    } u;
    int part[4][64];
    u64 selw[MW2];
    u64 validwLDS[MW2];
    u64 ballots[4];
    u64 keyRed[4];
    u64 winKeySh;
    int cntSh;
    int shC, shMsel, shTotal;
    int lsSh;
};

// sense-reversing grid barrier; only t0 touches the atomics
__device__ __forceinline__ void gbar(Bar* bar, int* lsSh) {
    __syncthreads();
    if (threadIdx.x == 0) {
        int s = *lsSh ^ 1;
        *lsSh = s;
        int old = __hip_atomic_fetch_add(&bar->cnt, 1, __ATOMIC_ACQ_REL,
                                         __HIP_MEMORY_SCOPE_AGENT);
        if (old == NB - 1) {
            __hip_atomic_store(&bar->cnt, 0, __ATOMIC_RELAXED, __HIP_MEMORY_SCOPE_AGENT);
            __hip_atomic_store(&bar->sense, s, __ATOMIC_RELEASE, __HIP_MEMORY_SCOPE_AGENT);
        } else {
            long long it = 0;
            while (__hip_atomic_load(&bar->sense, __ATOMIC_ACQUIRE,
                                     __HIP_MEMORY_SCOPE_AGENT) != s) {
                __builtin_amdgcn_s_sleep(1);
                if (++it > SPIN_CAP) break;        // escape hatch: fail, don't hang
            }
        }
    }
    __syncthreads();
}

__global__ __launch_bounds__(NT) void nms_mega_kernel(
        const float* __restrict__ scores, const float* __restrict__ scoreThrPtr,
        const float* __restrict__ boxes, const float* __restrict__ iouThrPtr,
        int* __restrict__ slices, Bar* __restrict__ bar,
        u64* __restrict__ ckeys, float4* __restrict__ sboxes,
        int* __restrict__ sorig, u64* __restrict__ maskT, u64* __restrict__ diagT,
        int* __restrict__ out, int N, int maxOut) {
    __shared__ SM sm;
    int tid = threadIdx.x, lane = tid & 63, wave = tid >> 6, bid = blockIdx.x;

    // ---- barrier attach / one-time magic-guarded init (handles 0xAA poison) ----
    if (bid == 0 && tid == 0) {
        if (__hip_atomic_load(&bar->ready, __ATOMIC_ACQUIRE, __HIP_MEMORY_SCOPE_AGENT)
            != BAR_MAGIC) {
            __hip_atomic_store(&bar->cnt, 0, __ATOMIC_RELAXED, __HIP_MEMORY_SCOPE_AGENT);
            __hip_atomic_store(&bar->sense, 0, __ATOMIC_RELAXED, __HIP_MEMORY_SCOPE_AGENT);
            __hip_atomic_store(&bar->ready, BAR_MAGIC, __ATOMIC_RELEASE,
                               __HIP_MEMORY_SCOPE_AGENT);
        }
    }
    if (tid == 0) {
        long long it = 0;
        while (__hip_atomic_load(&bar->ready, __ATOMIC_ACQUIRE,
                                 __HIP_MEMORY_SCOPE_AGENT) != BAR_MAGIC) {
            __builtin_amdgcn_s_sleep(1);
            if (++it > SPIN_CAP) break;
        }
        sm.lsSh = __hip_atomic_load(&bar->sense, __ATOMIC_RELAXED,
                                    __HIP_MEMORY_SCOPE_AGENT);
    }
    __syncthreads();

    float sThr = *scoreThrPtr;

    // ---- phase 1: histogram (blocks 0..7, LDS-local, private global slices) ----
    if (bid < HIST_BLOCKS) {
        for (int b = tid; b < 4096; b += NT) sm.u.bins[b] = 0;
        __syncthreads();
        for (int i = bid * NT + tid; i < N; i += HIST_BLOCKS * NT) {
            unsigned ud = score_ud(scores[i], sThr);
            if (ud != 0xFFFFFFFFu) atomicAdd(&sm.u.bins[ud >> 20], 1);
        }
        __syncthreads();
        int* myslice = slices + bid * 4096;
        for (int b = tid; b < 4096; b += NT) myslice[b] = sm.u.bins[b];
    }
    if (bid == 0 && tid == 0)
        __hip_atomic_store(&bar->ticket, 0, __ATOMIC_RELAXED, __HIP_MEMORY_SCOPE_AGENT);
    gbar(bar, &sm.lsSh);                           // B1: slices + ticket=0 visible

    // ---- phase 2: every block: slice-reduce (int4 unrolled) + cutoff ----
    {
        const int4* sl = (const int4*)slices;      // [HIST_BLOCKS][1024] int4
        int4* bo = (int4*)sm.u.bins;
#pragma unroll
        for (int k = 0; k < 4; ++k) {
            int p = k * NT + tid;
            int4 a = sl[p];
            int4 v1 = sl[1024 + p];
            int4 v2 = sl[2 * 1024 + p];
            int4 v3 = sl[3 * 1024 + p];
            int4 v4 = sl[4 * 1024 + p];
            int4 v5 = sl[5 * 1024 + p];
            int4 v6 = sl[6 * 1024 + p];
            int4 v7 = sl[7 * 1024 + p];
            a.x += v1.x + v2.x + v3.x + v4.x + v5.x + v6.x + v7.x;
            a.y += v1.y + v2.y + v3.y + v4.y + v5.y + v6.y + v7.y;
            a.z += v1.z + v2.z + v3.z + v4.z + v5.z + v6.z + v7.z;
            a.w += v1.w + v2.w + v3.w + v4.w + v5.w + v6.w + v7.w;
            bo[p] = a;
        }
    }
    __syncthreads();
    if (tid < 64) {                                // wave0: cutoff (R11-proven)
        int base = lane * 64;
        int sum = 0;
        for (int b = 0; b < 64; ++b) sum += sm.u.bins[base + ((b + lane) & 63)];
        int incl = sum;
        for (int off = 1; off < 64; off <<= 1) {
            int o = __shfl_up(incl, off, 64);
            if (lane >= off) incl += o;
        }
        int total = __shfl(incl, 63, 64);
        int need = (TOPK < total) ? TOPK : total;
        u64 ok = __ballot(incl >= need);
        int L = (ok != 0ull) ? (int)__builtin_ctzll(ok) : 0;
        if (lane == L) {
            int acc = incl - sum;                  // exclusive prefix
            int C = base, Msel = acc;
            for (int b = 0; b < 64; ++b) {
                acc += sm.u.bins[base + b];
                if (acc >= need) { C = base + b; Msel = acc; break; }
            }
            if (need <= 0) { C = -1; Msel = 0; }
            sm.shC = C;
            sm.shMsel = Msel;
        }
        if (lane == 0) sm.shTotal = total;
    }
    __syncthreads();

    // ---- phase 3: compact (grid-stride, wave-agg global ticket) ----
    {
        int C = sm.shC;
        for (int i0 = bid * NT; i0 < N; i0 += NB * NT) {
            int i = i0 + tid;
            bool sel = false;
            unsigned ud = 0;
            if (i < N) {
                ud = score_ud(scores[i], sThr);
                sel = (ud != 0xFFFFFFFFu) && ((int)(ud >> 20) <= C);
            }
            u64 ball = __ballot(sel);
            if (ball) {
                int cntw = __popcll(ball);
                int base = 0;
                if (lane == 0)
                    base = __hip_atomic_fetch_add(&bar->ticket, cntw, __ATOMIC_RELAXED,
                                                  __HIP_MEMORY_SCOPE_AGENT);
                base = __shfl(base, 0, 64);
                if (sel) {
                    int slot = base + __popcll(ball & ((1ull << lane) - 1ull));
                    if (slot < CAND) ckeys[slot] = ((u64)ud << 32) | (unsigned)i;
                }
            }
        }
    }
    gbar(bar, &sm.lsSh);                           // B2: ckeys visible

    // ---- phase 4: rank-and-gather (block owns candidates [bid*64, bid*64+64)) ----
    {
        int Msel = sm.shMsel;
        if (Msel > CAND) Msel = CAND;
        for (int j = tid; j < Msel; j += NT) sm.u.rkeys[j] = ckeys[j];
        __syncthreads();
        int i = bid * 64 + lane;
        u64 key = (i < Msel) ? sm.u.rkeys[i] : ~0ull;
        int chunk = (Msel + 3) >> 2;
        int j0 = wave * chunk;
        int j1 = j0 + chunk; if (j1 > Msel) j1 = Msel;
        int r = 0;
#pragma unroll 4
        for (int j = j0; j < j1; ++j) r += (sm.u.rkeys[j] < key) ? 1 : 0;
        sm.part[wave][lane] = r;
        __syncthreads();
        if (wave == 0 && i < Msel) {
            int rank = sm.part[0][lane] + sm.part[1][lane] +
                       sm.part[2][lane] + sm.part[3][lane];
            if (rank < TOPK) {
                int idx = (int)(key & 0xFFFFFFFFu);
                sboxes[rank] = ((const float4*)boxes)[idx];
                sorig[rank] = idx;
            }
        }
    }
    gbar(bar, &sm.lsSh);                           // B3: sboxes/sorig visible

    // ---- phase 5: transposed IoU mask (3 rounds x 256 wave-groups) ----
    {
        float iThr = *iouThrPtr;
        for (int round = 0; round < 3; ++round) {
            int t = round * (NB * 4) + bid * 4 + wave;
            bool act = (t < NTILES);
            int wi = 0, tt = act ? t : 0;
            if (act) { while (tt >= MW2 - wi) { tt -= MW2 - wi; ++wi; } }
            int wj = wi + tt;
            if (act) {
                float4 jb = sboxes[(wj << 6) + lane];
                sm.u.mk.jx1[wave][lane] = jb.x; sm.u.mk.jy1[wave][lane] = jb.y;
                sm.u.mk.jx2[wave][lane] = jb.z; sm.u.mk.jy2[wave][lane] = jb.w;
                sm.u.mk.ja[wave][lane] = (jb.z - jb.x) * (jb.w - jb.y);
            }
            __syncthreads();
            if (act) {
                int i = (wi << 6) + lane;
                float4 ib = sboxes[i];
                float ia = (ib.z - ib.x) * (ib.w - ib.y);
                int j0 = wj << 6;
                u64 bits = 0;
                for (int jj = 0; jj < 64; ++jj) {
                    int j = j0 + jj;
                    if (j > i) {
                        float xx1 = fmaxf(ib.x, sm.u.mk.jx1[wave][jj]);
                        float yy1 = fmaxf(ib.y, sm.u.mk.jy1[wave][jj]);
                        float xx2 = fminf(ib.z, sm.u.mk.jx2[wave][jj]);
                        float yy2 = fminf(ib.w, sm.u.mk.jy2[wave][jj]);
                        float ww = fmaxf(xx2 - xx1, 0.0f);
                        float hh = fmaxf(yy2 - yy1, 0.0f);
                        float inter = ww * hh;
                        float uni = fmaxf(ia + sm.u.mk.ja[wave][jj] - inter, 1e-6f);
                        if (inter / uni >= iThr) bits |= 1ull << jj;
                    }
                }
                sm.u.mk.rowLDS[wave][lane] = bits;
            }
            __syncthreads();
            if (act) {
                u64 col = 0;
                for (int r = 0; r < 64; ++r)
                    col |= ((sm.u.mk.rowLDS[wave][r] >> lane) & 1ull) << r;
                maskT[(size_t)((wj << 6) + lane) * MW2 + wi] = col;
                if (wi == wj) diagT[(wi << 6) + lane] = col;
            }
            __syncthreads();
        }
    }
    gbar(bar, &sm.lsSh);                           // B4: maskT/diagT visible

    // ---- phase 6: scan + fallback (block 0 only; others done) ----
    if (bid != 0) return;

    int Msel = sm.shMsel;
    int V = (Msel < TOPK) ? Msel : TOPK;           // valid = ranks [0, V)
    for (int k = tid; k < TOPK; k += NT) sm.u.sc.diagLDS[k] = diagT[k];
    if (tid < MW2) {
        int lo = tid * 64;
        u64 vw = (V >= lo + 64) ? ~0ull : ((V > lo) ? ((1ull << (V - lo)) - 1ull) : 0ull);
        sm.validwLDS[tid] = vw;
        sm.selw[tid] = 0ull;
    }
    if (tid == 0) sm.cntSh = 0;

    ulonglong2 a0, a1, a2, a3;
    int cc = tid >> 2, g = tid & 3;
    {
        const ulonglong2* p = (const ulonglong2*)(maskT + (size_t)cc * MW2 + g * 8);
        a0 = p[0]; a1 = p[1]; a2 = p[2]; a3 = p[3];
    }
    __syncthreads();

    int cnt = 0;
    for (int w = 0; w < MW2; ++w) {
        {
            u64 wd0 = a0.x, wd1 = a0.y, wd2 = a1.x, wd3 = a1.y;
            u64 wd4 = a2.x, wd5 = a2.y, wd6 = a3.x, wd7 = a3.y;
            int wr0 = g * 8;
            u64 acc = 0;
            if (wr0 + 0 < w) acc |= wd0 & sm.selw[wr0 + 0];
            if (wr0 + 1 < w) acc |= wd1 & sm.selw[wr0 + 1];
            if (wr0 + 2 < w) acc |= wd2 & sm.selw[wr0 + 2];
            if (wr0 + 3 < w) acc |= wd3 & sm.selw[wr0 + 3];
            if (wr0 + 4 < w) acc |= wd4 & sm.selw[wr0 + 4];
            if (wr0 + 5 < w) acc |= wd5 & sm.selw[wr0 + 5];
            if (wr0 + 6 < w) acc |= wd6 & sm.selw[wr0 + 6];
            if (wr0 + 7 < w) acc |= wd7 & sm.selw[wr0 + 7];
            acc |= __shfl_xor(acc, 1, 64);
            acc |= __shfl_xor(acc, 2, 64);
            u64 B = __ballot(acc != 0ull);
            if (lane == 0) sm.ballots[wave] = B;
            if (w + 1 < MW2) {
                const ulonglong2* p =
                    (const ulonglong2*)(maskT + (size_t)((w + 1) * 64 + cc) * MW2 + g * 8);
                a0 = p[0]; a1 = p[1]; a2 = p[2]; a3 = p[3];
            }
        }
        __syncthreads();
        if (wave == 0) {
            u64 bv = sm.ballots[lane >> 4];
            bool crossk = (bv >> ((lane & 15) << 2)) & 1ull;
            bool alv = ((sm.validwLDS[w] >> lane) & 1ull) && !crossk;
            u64 inm = sm.u.sc.diagLDS[(w << 6) | lane];
            u64 sel = __ballot(alv);
            for (int it = 0; it < 64; ++it) {      // fixpoint; monotone shrink
                bool killed = (inm & sel) != 0ull;
                u64 ns = __ballot(alv && !killed);
                if (ns == sel) break;
                sel = ns;
            }
            int room = maxOut - cnt;
            int tot = __popcll(sel);
            u64 below = (1ull << lane) - 1ull;
            if (tot > room) {
                bool keep = ((sel >> lane) & 1ull) && (__popcll(sel & below) < room);
                sel = __ballot(keep);
                tot = room;
            }
            if ((sel >> lane) & 1ull) {
                int pos = cnt + __popcll(sel & below);
                sm.u.sc.selLDS[pos] = (w << 6) | lane;
            }
            if (lane == 0) { sm.selw[w] = sel; sm.cntSh = cnt + tot; }
        }
        __syncthreads();
        cnt = sm.cntSh;
        if (cnt >= maxOut) break;
    }

    int vt = sm.shTotal;
    bool f2 = (sm.shMsel > CAND);
    bool complete = (!f2) && ((cnt >= maxOut) || (V >= vt));
    if (complete) {                                // uniform
        for (int k = tid; k < cnt; k += NT) out[k] = sorig[sm.u.sc.selLDS[k]];
        for (int k = cnt + tid; k < maxOut; k += NT) out[k] = 0;
        if (tid == 0) out[maxOut] = cnt;
        return;                                    // uniform return
    }

    // ---- exact fallback: repeated argmax greedy NMS (R8-proven, 256-thread) ----
    float iThr = *iouThrPtr;
    for (int e0 = wave << 6; e0 < N; e0 += NT) {
        int e = e0 + lane;
        bool a = (e < N) && (scores[e] > sThr);
        u64 ball = __ballot(a);
        if (lane == 0) sm.u.sc.aliveW[e0 >> 6] = ball;
    }
    __syncthreads();
    int fcnt = 0;
    while (fcnt < maxOut) {
        u64 best = 0;
        for (int e = tid; e < N; e += NT) {
            if ((sm.u.sc.aliveW[e >> 6] >> (e & 63)) & 1ull) {
                float s = scores[e];
                unsigned u = __float_as_uint(s);
                u ^= (u >> 31) ? 0xFFFFFFFFu : 0x80000000u;
                u64 k = ((u64)u << 32) | (unsigned)(~e);
                if (k > best) best = k;
            }
        }
#pragma unroll
        for (int off = 32; off >= 1; off >>= 1) {
            u64 o = __shfl_xor(best, off, 64);
            if (o > best) best = o;
        }
        if (lane == 0) sm.keyRed[wave] = best;
        __syncthreads();
        if (tid == 0) {
            u64 b = 0;
            for (int p = 0; p < 4; ++p) if (sm.keyRed[p] > b) b = sm.keyRed[p];
            sm.winKeySh = b;
        }
        __syncthreads();
        u64 wk = sm.winKeySh;
        if (wk == 0ull) break;
        int win = (int)(~(unsigned)wk);
        if (tid == 0) out[fcnt] = win;
        ++fcnt;
        float4 wb = ((const float4*)boxes)[win];
        float wa = (wb.z - wb.x) * (wb.w - wb.y);
        for (int e0 = wave << 6; e0 < N; e0 += NT) {
            int e = e0 + lane;
            bool kill = false;
            if (e < N && ((sm.u.sc.aliveW[e0 >> 6] >> lane) & 1ull)) {
                if (e == win) kill = true;
                else {
                    float4 bb = ((const float4*)boxes)[e];
                    float xx1 = fmaxf(wb.x, bb.x), yy1 = fmaxf(wb.y, bb.y);
                    float xx2 = fminf(wb.z, bb.z), yy2 = fminf(wb.w, bb.w);
                    float inter = fmaxf(xx2 - xx1, 0.0f) * fmaxf(yy2 - yy1, 0.0f);
                    float ba = (bb.z - bb.x) * (bb.w - bb.y);
                    float uni = fmaxf(wa + ba - inter, 1e-6f);
                    kill = (inter / uni >= iThr);
                }
            }
            u64 kb = __ballot(kill);
            if (lane == 0 && kb) sm.u.sc.aliveW[e0 >> 6] &= ~kb;
        }
        __syncthreads();
    }
    for (int k = fcnt + tid; k < maxOut; k += NT) out[k] = 0;
    if (tid == 0) out[maxOut] = fcnt;
}

// ---------------- launch ----------------
extern "C" void kernel_launch(void* const* d_in, const int* in_sizes, int n_in,
                              void* d_out, int out_size, void* d_ws, size_t ws_size,
                              hipStream_t stream) {
    const float* boxes       = (const float*)d_in[0];
    const float* scores      = (const float*)d_in[1];
    const float* iouThrPtr   = (const float*)d_in[3];
    const float* scoreThrPtr = (const float*)d_in[4];

    int N = in_sizes[0] / 4;
    int maxOut = out_size - 1;

    char* ws = (char*)d_ws;
    size_t off = 0;
    auto take = [&](size_t b) { void* p = ws + off; off = (off + b + 255) & ~(size_t)255; return p; };
    Bar*    bar    = (Bar*)   take(256);
    int*    slices = (int*)   take((size_t)HIST_BLOCKS * 4096 * 4);
    u64*    ckeys  = (u64*)   take((size_t)CAND * 8);
    float4* sboxes = (float4*)take((size_t)TOPK * 16);
    int*    sorig  = (int*)   take((size_t)TOPK * 4);
    u64*    maskT  = (u64*)   take((size_t)TOPK * MW2 * 8);
    u64*    diagT  = (u64*)   take((size_t)MW2 * 64 * 8);
    (void)ws_size;
    int* outp = (int*)d_out;

    void* args[] = {
        (void*)&scores, (void*)&scoreThrPtr, (void*)&boxes, (void*)&iouThrPtr,
        (void*)&slices, (void*)&bar, (void*)&ckeys, (void*)&sboxes,
        (void*)&sorig, (void*)&maskT, (void*)&diagT, (void*)&outp,
        (void*)&N, (void*)&maxOut
    };
    hipLaunchCooperativeKernel((void*)nms_mega_kernel, dim3(NB), dim3(NT), args, 0, stream);
}

// Round 19
// 83.577 us; speedup vs baseline: 1.4559x; 1.4559x over previous
//
#include <hip/hip_runtime.h>
#include <cstdint>

typedef unsigned long long u64;

#define TOPK 2048          // candidate window for mask+scan
#define MW2 (TOPK / 64)    // 32 suppression words
#define CAND 8192          // max candidates (sampling slack)
#define NSEG 32            // compact blocks / segments
#define SEGSZ (CAND / NSEG)
#define SAMPLE 512
#define RANKB (CAND / 64)  // 128 rank blocks
#define NTILES ((MW2 * (MW2 + 1)) / 2)   // 528 triangular mask tiles
#define FB_WORDS 1024
#define SCAN_NT 256

// meta (ints): [1]=validTotal [2]=Msel [3]=flag2 [8+b]=segCnt [40+b]=validCnt [72+b]=ovf

__device__ __forceinline__ unsigned score_ud(float s, float thr) {
    unsigned u = __float_as_uint(s);
    u ^= (u >> 31) ? 0xFFFFFFFFu : 0x80000000u;   // orderable ascending
    unsigned ud = ~u;                              // ascending ud = descending score
    if (!(s > thr)) ud = 0xFFFFFFFFu;              // below threshold -> invalid
    return ud;
}

// ---- 1. compact: sampled cutoff (redundant per block) + segmented compaction ----
__global__ __launch_bounds__(256) void compact_kernel(
        const float* __restrict__ scores, const float* __restrict__ thrPtr,
        int* __restrict__ meta, u64* __restrict__ ckeys, int N) {
    __shared__ u64 skeys[SAMPLE];
    __shared__ int shC, validSamp, ticket, validC;
    int tid = threadIdx.x, lane = tid & 63, bid = blockIdx.x;
    float thr = *thrPtr;
    if (tid == 0) { shC = 0xFFE; validSamp = 0; ticket = 0; validC = 0; }
    __syncthreads();
    // phase A: load strided samples, build keys
    for (int k = tid; k < SAMPLE; k += 256) {
        int idx = (int)(((long long)k * N) / SAMPLE);
        unsigned ud = score_ud(scores[idx], thr);
        skeys[k] = ((u64)ud << 32) | (unsigned)idx;
    }
    __syncthreads();
    // phase B: rank samples in-sample; the (tr-1)-ranked valid sample's prefix = C
    int tr = (int)((3048LL * SAMPLE + N - 1) / N);
    if (tr < 1) tr = 1; if (tr > SAMPLE) tr = SAMPLE;
    int myv = 0;
    for (int k = tid; k < SAMPLE; k += 256) {
        u64 key = skeys[k];
        bool valid = ((unsigned)(key >> 32) != 0xFFFFFFFFu);
        if (valid) ++myv;
        int r = 0;
#pragma unroll 8
        for (int j = 0; j < SAMPLE; ++j) r += (skeys[j] < key) ? 1 : 0;
        if (valid && r == tr - 1) shC = (int)(key >> 52);
    }
    if (myv) atomicAdd(&validSamp, myv);
    __syncthreads();
    int sv = validSamp;
    int C = (N <= CAND || ((long long)sv * N) / SAMPLE < 6500) ? 0xFFE : shC;
    // phase C: own index range -> private segment (no global atomics)
    int lo = (int)(((long long)N * bid) / NSEG);
    int hi = (int)(((long long)N * (bid + 1)) / NSEG);
    for (int i0 = lo; i0 < hi; i0 += 256) {
        int i = i0 + tid;
        bool inb = (i < hi);
        unsigned ud = 0;
        bool valid = false, sel = false;
        if (inb) {
            ud = score_ud(scores[i], thr);
            valid = (ud != 0xFFFFFFFFu);
            sel = valid && ((int)(ud >> 20) <= C);
        }
        u64 vb = __ballot(valid);
        u64 sb = __ballot(sel);
        if (lane == 0 && vb) atomicAdd(&validC, __popcll(vb));
        if (sb) {
            int base = 0;
            if (lane == 0) base = atomicAdd(&ticket, __popcll(sb));
            base = __shfl(base, 0, 64);
            if (sel) {
                int slot = base + __popcll(sb & ((1ull << lane) - 1ull));
                if (slot < SEGSZ) ckeys[bid * SEGSZ + slot] = ((u64)ud << 32) | (unsigned)i;
            }
        }
    }
    __syncthreads();
    if (tid == 0) {
        int t = ticket;
        meta[8 + bid]  = (t < SEGSZ) ? t : SEGSZ;
        meta[40 + bid] = validC;
        meta[72 + bid] = (t > SEGSZ) ? 1 : 0;
    }
}

// ---- 2. rank-and-gather over stitched segments (order-invariant rank) ----
__global__ __launch_bounds__(256) void rank_gather_kernel(
        const u64* __restrict__ ckeys, int* __restrict__ meta,
        const float* __restrict__ boxes,
        float4* __restrict__ sboxes, int* __restrict__ sorig) {
    __shared__ u64 lk[CAND];                 // 64 KB
    __shared__ int segOff[NSEG + 1];
    __shared__ int part[4][64];
    __shared__ int shVT, shF2;
    int tid = threadIdx.x, lane = tid & 63, wave = tid >> 6, bid = blockIdx.x;
    if (tid < 64) {
        int c = (lane < NSEG) ? meta[8 + lane]  : 0;
        int f = (lane < NSEG) ? meta[72 + lane] : 0;
        int v = (lane < NSEG) ? meta[40 + lane] : 0;
        int incl = c;
        for (int off = 1; off < 64; off <<= 1) {
            int o = __shfl_up(incl, off, 64);
            if (lane >= off) incl += o;
        }
        if (lane < NSEG) segOff[lane] = incl - c;       // exclusive prefix
        if (lane == NSEG - 1) segOff[NSEG] = incl;      // total = Msel
#pragma unroll
        for (int off = 32; off >= 1; off >>= 1) {
            f |= __shfl_xor(f, off, 64);
            v += __shfl_xor(v, off, 64);
        }
        if (lane == 0) { shF2 = f; shVT = v; }
    }
    __syncthreads();
    int Msel = segOff[NSEG];
    if (bid == 0 && tid == 0) { meta[1] = shVT; meta[2] = Msel; meta[3] = shF2; }
    if (bid * 64 >= Msel) return;                       // uniform (after publish)
    for (int s = 0; s < NSEG; ++s) {                    // stitch segments into lk
        int base = segOff[s];
        int cnt = segOff[s + 1] - base;
        for (int j = tid; j < cnt; j += 256) lk[base + j] = ckeys[s * SEGSZ + j];
    }
    __syncthreads();
    int i = bid * 64 + lane;
    u64 key = (i < Msel) ? lk[i] : ~0ull;
    int chunk = (Msel + 3) >> 2;
    int j0 = wave * chunk;
    int j1 = j0 + chunk; if (j1 > Msel) j1 = Msel;
    int r = 0;
#pragma unroll 4
    for (int j = j0; j < j1; ++j) r += (lk[j] < key) ? 1 : 0;
    part[wave][lane] = r;
    __syncthreads();
    if (wave == 0 && i < Msel) {
        int rank = part[0][lane] + part[1][lane] + part[2][lane] + part[3][lane];
        if (rank < TOPK) {
            int idx = (int)(key & 0xFFFFFFFFu);
            sboxes[rank] = ((const float4*)boxes)[idx];
            sorig[rank] = idx;
        }
    }
}

// ---- 3. transposed IoU mask, linear 528-block triangular grid (R17-proven) ----
__global__ __launch_bounds__(64) void mask2_kernel(
        const float4* __restrict__ sboxes, const float* __restrict__ iouThrPtr,
        u64* __restrict__ maskT, u64* __restrict__ diagT) {
    __shared__ float jx1[64], jy1[64], jx2[64], jy2[64], ja[64];
    __shared__ u64 rowLDS[64];
    int t = threadIdx.x;
    int wi = 0, tt = blockIdx.x;
    while (tt >= MW2 - wi) { tt -= MW2 - wi; ++wi; }
    int wj = wi + tt;
    int j0 = wj << 6;
    float4 jb = sboxes[j0 + t];
    jx1[t] = jb.x; jy1[t] = jb.y; jx2[t] = jb.z; jy2[t] = jb.w;
    ja[t] = (jb.z - jb.x) * (jb.w - jb.y);
    __syncthreads();
    int i = (wi << 6) + t;
    float thr = *iouThrPtr;
    float4 ib = sboxes[i];
    float ia = (ib.z - ib.x) * (ib.w - ib.y);
    u64 bits = 0;
    for (int jj = 0; jj < 64; ++jj) {
        int j = j0 + jj;
        if (j > i) {
            float xx1 = fmaxf(ib.x, jx1[jj]);
            float yy1 = fmaxf(ib.y, jy1[jj]);
            float xx2 = fminf(ib.z, jx2[jj]);
            float yy2 = fminf(ib.w, jy2[jj]);
            float ww = fmaxf(xx2 - xx1, 0.0f);
            float hh = fmaxf(yy2 - yy1, 0.0f);
            float inter = ww * hh;
            float uni = fmaxf(ia + ja[jj] - inter, 1e-6f);
            if (inter / uni >= thr) bits |= 1ull << jj;
        }
    }
    rowLDS[t] = bits;
    __syncthreads();
    u64 col = 0;
    for (int r = 0; r < 64; ++r) col |= ((rowLDS[r] >> t) & 1ull) << r;
    maskT[(size_t)(j0 + t) * MW2 + wi] = col;
    if (wi == wj) diagT[(wi << 6) + t] = col;
}

// ---- 4. chunk-wise greedy scan (R17-proven 256-thread core) + inline fallback ----
__global__ __launch_bounds__(SCAN_NT) void scan2_kernel(
        const u64* __restrict__ maskT, const u64* __restrict__ diagT,
        const int* __restrict__ sorig, const int* __restrict__ meta,
        const float* __restrict__ boxes, const float* __restrict__ scores,
        const float* __restrict__ iouThrPtr, const float* __restrict__ scoreThrPtr,
        int* __restrict__ out, int N, int maxOut) {
    __shared__ u64 diagLDS[TOPK];
    __shared__ u64 selw[MW2];
    __shared__ u64 validwLDS[MW2];
    __shared__ u64 ballots[4];
    __shared__ int selLDS[TOPK];
    __shared__ int cntSh;
    __shared__ u64 aliveW[FB_WORDS];
    __shared__ u64 keyRed[4];
    __shared__ u64 winKeySh;
    int tid = threadIdx.x, lane = tid & 63, wave = tid >> 6;

    int Msel = meta[2];
    int V = (Msel < TOPK) ? Msel : TOPK;           // valid = ranks [0, V)
    for (int k = tid; k < TOPK; k += SCAN_NT) diagLDS[k] = diagT[k];
    if (tid < MW2) {
        int lo = tid * 64;
        u64 vw = (V >= lo + 64) ? ~0ull : ((V > lo) ? ((1ull << (V - lo)) - 1ull) : 0ull);
        validwLDS[tid] = vw;
        selw[tid] = 0ull;
    }
    if (tid == 0) cntSh = 0;

    ulonglong2 a0, a1, a2, a3;
    int cc = tid >> 2, g = tid & 3;
    {
        const ulonglong2* p = (const ulonglong2*)(maskT + (size_t)cc * MW2 + g * 8);
        a0 = p[0]; a1 = p[1]; a2 = p[2]; a3 = p[3];
    }
    __syncthreads();

    int cnt = 0;
    for (int w = 0; w < MW2; ++w) {
        {
            u64 wd0 = a0.x, wd1 = a0.y, wd2 = a1.x, wd3 = a1.y;
            u64 wd4 = a2.x, wd5 = a2.y, wd6 = a3.x, wd7 = a3.y;
            int wr0 = g * 8;
            u64 acc = 0;
            if (wr0 + 0 < w) acc |= wd0 & selw[wr0 + 0];
            if (wr0 + 1 < w) acc |= wd1 & selw[wr0 + 1];
            if (wr0 + 2 < w) acc |= wd2 & selw[wr0 + 2];
            if (wr0 + 3 < w) acc |= wd3 & selw[wr0 + 3];
            if (wr0 + 4 < w) acc |= wd4 & selw[wr0 + 4];
            if (wr0 + 5 < w) acc |= wd5 & selw[wr0 + 5];
            if (wr0 + 6 < w) acc |= wd6 & selw[wr0 + 6];
            if (wr0 + 7 < w) acc |= wd7 & selw[wr0 + 7];
            acc |= __shfl_xor(acc, 1, 64);
            acc |= __shfl_xor(acc, 2, 64);
            u64 B = __ballot(acc != 0ull);
            if (lane == 0) ballots[wave] = B;
            if (w + 1 < MW2) {
                const ulonglong2* p = (const ulonglong2*)(maskT + (size_t)((w + 1) * 64 + cc) * MW2 + g * 8);
                a0 = p[0]; a1 = p[1]; a2 = p[2]; a3 = p[3];
            }
        }
        __syncthreads();
        if (wave == 0) {
            u64 bv = ballots[lane >> 4];
            bool crossk = (bv >> ((lane & 15) << 2)) & 1ull;
            bool alv = ((validwLDS[w] >> lane) & 1ull) && !crossk;
            u64 inm = diagLDS[(w << 6) | lane];
            u64 sel = __ballot(alv);
            for (int it = 0; it < 64; ++it) {      // fixpoint; monotone shrink
                bool killed = (inm & sel) != 0ull;
                u64 ns = __ballot(alv && !killed);
                if (ns == sel) break;
                sel = ns;
            }
            int room = maxOut - cnt;
            int tot = __popcll(sel);
            u64 below = (1ull << lane) - 1ull;
            if (tot > room) {
                bool keep = ((sel >> lane) & 1ull) && (__popcll(sel & below) < room);
                sel = __ballot(keep);
                tot = room;
            }
            if ((sel >> lane) & 1ull) {
                int pos = cnt + __popcll(sel & below);
                selLDS[pos] = (w << 6) | lane;
            }
            if (lane == 0) { selw[w] = sel; cntSh = cnt + tot; }
        }
        __syncthreads();
        cnt = cntSh;
        if (cnt >= maxOut) break;
    }

    int vt = meta[1];
    int f2 = meta[3];
    bool complete = (f2 == 0) && ((cnt >= maxOut) || (V >= vt));
    if (complete) {                                // uniform
        for (int k = tid; k < cnt; k += SCAN_NT) out[k] = sorig[selLDS[k]];
        for (int k = cnt + tid; k < maxOut; k += SCAN_NT) out[k] = 0;
        if (tid == 0) out[maxOut] = cnt;
        return;                                    // uniform return
    }

    // ---- exact fallback: repeated argmax greedy NMS (proven, 256-thread) ----
    float sThr = *scoreThrPtr, iThr = *iouThrPtr;
    for (int e0 = wave << 6; e0 < N; e0 += SCAN_NT) {
        int e = e0 + lane;
        bool a = (e < N) && (scores[e] > sThr);
        u64 ball = __ballot(a);
        if (lane == 0) aliveW[e0 >> 6] = ball;
    }
    __syncthreads();
    int fcnt = 0;
    while (fcnt < maxOut) {
        u64 best = 0;
        for (int e = tid; e < N; e += SCAN_NT) {
            if ((aliveW[e >> 6] >> (e & 63)) & 1ull) {
                float s = scores[e];
                unsigned u = __float_as_uint(s);
                u ^= (u >> 31) ? 0xFFFFFFFFu : 0x80000000u;
                u64 k = ((u64)u << 32) | (unsigned)(~e);
                if (k > best) best = k;
            }
        }
#pragma unroll
        for (int off = 32; off >= 1; off >>= 1) {
            u64 o = __shfl_xor(best, off, 64);
            if (o > best) best = o;
        }
        if (lane == 0) keyRed[wave] = best;
        __syncthreads();
        if (tid == 0) {
            u64 b = 0;
            for (int p = 0; p < 4; ++p) if (keyRed[p] > b) b = keyRed[p];
            winKeySh = b;
        }
        __syncthreads();
        u64 wk = winKeySh;
        if (wk == 0ull) break;
        int win = (int)(~(unsigned)wk);
        if (tid == 0) out[fcnt] = win;
        ++fcnt;
        float4 wb = ((const float4*)boxes)[win];
        float wa = (wb.z - wb.x) * (wb.w - wb.y);
        for (int e0 = wave << 6; e0 < N; e0 += SCAN_NT) {
            int e = e0 + lane;
            bool kill = false;
            if (e < N && ((aliveW[e0 >> 6] >> lane) & 1ull)) {
                if (e == win) kill = true;
                else {
                    float4 bb = ((const float4*)boxes)[e];
                    float xx1 = fmaxf(wb.x, bb.x), yy1 = fmaxf(wb.y, bb.y);
                    float xx2 = fminf(wb.z, bb.z), yy2 = fminf(wb.w, bb.w);
                    float inter = fmaxf(xx2 - xx1, 0.0f) * fmaxf(yy2 - yy1, 0.0f);
                    float ba = (bb.z - bb.x) * (bb.w - bb.y);
                    float uni = fmaxf(wa + ba - inter, 1e-6f);
                    kill = (inter / uni >= iThr);
                }
            }
            u64 kb = __ballot(kill);
            if (lane == 0 && kb) aliveW[e0 >> 6] &= ~kb;
        }
        __syncthreads();
    }
    for (int k = fcnt + tid; k < maxOut; k += SCAN_NT) out[k] = 0;
    if (tid == 0) out[maxOut] = fcnt;
}

// ---------------- launch ----------------
extern "C" void kernel_launch(void* const* d_in, const int* in_sizes, int n_in,
                              void* d_out, int out_size, void* d_ws, size_t ws_size,
                              hipStream_t stream) {
    const float* boxes       = (const float*)d_in[0];
    const float* scores      = (const float*)d_in[1];
    const float* iouThrPtr   = (const float*)d_in[3];
    const float* scoreThrPtr = (const float*)d_in[4];

    int N = in_sizes[0] / 4;
    int maxOut = out_size - 1;

    char* ws = (char*)d_ws;
    size_t off = 0;
    auto take = [&](size_t b) { void* p = ws + off; off = (off + b + 255) & ~(size_t)255; return p; };
    int*    meta   = (int*)   take(1024);
    u64*    ckeys  = (u64*)   take((size_t)CAND * 8);
    float4* sboxes = (float4*)take((size_t)TOPK * 16);
    int*    sorig  = (int*)   take((size_t)TOPK * 4);
    u64*    maskT  = (u64*)   take((size_t)TOPK * MW2 * 8);
    u64*    diagT  = (u64*)   take((size_t)MW2 * 64 * 8);
    (void)ws_size;

    compact_kernel<<<NSEG, 256, 0, stream>>>(scores, scoreThrPtr, meta, ckeys, N);
    rank_gather_kernel<<<RANKB, 256, 0, stream>>>(ckeys, meta, boxes, sboxes, sorig);
    mask2_kernel<<<NTILES, 64, 0, stream>>>(sboxes, iouThrPtr, maskT, diagT);
    scan2_kernel<<<1, SCAN_NT, 0, stream>>>(maskT, diagT, sorig, meta,
                                            boxes, scores, iouThrPtr, scoreThrPtr,
                                            (int*)d_out, N, maxOut);
}